// Round 1
// baseline (895.368 us; speedup 1.0000x reference)
//
#include <hip/hip_runtime.h>
#include <stdint.h>

#define NN 50000
#define NE 600000
#define DIM 128
#define BN_EPS 1e-5f
#define NB 16   // nodes per GEMM block

// ---------------- CSR build ----------------

__global__ void count_k(const int* __restrict__ dst, int* __restrict__ counts, int E) {
    int i = blockIdx.x * 256 + threadIdx.x;
    if (i < E) atomicAdd(&counts[dst[i]], 1);
}

// single-block exclusive scan over counts -> offsets (and cursor copy)
__global__ void scan_k(const int* __restrict__ counts, int* __restrict__ offsets,
                       int* __restrict__ cursor, int N) {
    __shared__ int lds[1024];
    __shared__ int base_s;
    if (threadIdx.x == 0) base_s = 0;
    __syncthreads();
    for (int start = 0; start < N; start += 1024) {
        int i = start + (int)threadIdx.x;
        int v = (i < N) ? counts[i] : 0;
        lds[threadIdx.x] = v;
        __syncthreads();
        for (int off = 1; off < 1024; off <<= 1) {
            int t = (threadIdx.x >= (unsigned)off) ? lds[threadIdx.x - off] : 0;
            __syncthreads();
            lds[threadIdx.x] += t;
            __syncthreads();
        }
        int incl = lds[threadIdx.x];
        int base = base_s;               // all threads read before update
        if (i < N) { int excl = base + incl - v; offsets[i] = excl; cursor[i] = excl; }
        __syncthreads();
        if (threadIdx.x == 0) base_s = base + lds[1023];
        __syncthreads();
    }
    if (threadIdx.x == 0) offsets[N] = base_s;
}

__global__ void fill_k(const int* __restrict__ dst, int* __restrict__ cursor,
                       int* __restrict__ eidx, int E) {
    int i = blockIdx.x * 256 + threadIdx.x;
    if (i < E) { int p = atomicAdd(&cursor[dst[i]], 1); eidx[p] = i; }
}

__global__ void ident_k(float* scale, float* shift) {
    int d = threadIdx.x;
    if (d < DIM) { scale[d] = 1.f; shift[d] = 0.f; }
}

// ---------------- per-layer kernels ----------------

// s[n] = xnorm[n] + sum_{e: dst=n} relu(xnorm[src_e] + eattr[e])
// where xnorm = x*scale + shift (BN folded into reads).
// block = 256 threads = 8 nodes x 32 lanes; each lane handles 4 features (float4)
__global__ __launch_bounds__(256) void aggregate_k(
        const float* __restrict__ x, const float* __restrict__ scale,
        const float* __restrict__ shift, const float* __restrict__ eattr,
        const int* __restrict__ srcs, const int* __restrict__ offsets,
        const int* __restrict__ eidx, float* __restrict__ sbuf, int N) {
    int lane = threadIdx.x & 31;
    int nloc = threadIdx.x >> 5;
    int n = blockIdx.x * 8 + nloc;
    if (n >= N) return;
    int f = lane * 4;
    float4 sc = *(const float4*)(scale + f);
    float4 sh = *(const float4*)(shift + f);
    float4 acc = make_float4(0.f, 0.f, 0.f, 0.f);
    int beg = offsets[n], end = offsets[n + 1];
    for (int k = beg; k < end; ++k) {
        int e = eidx[k];
        int s = srcs[e];
        float4 xv = *(const float4*)(x + (size_t)s * DIM + f);
        float4 ev = *(const float4*)(eattr + (size_t)e * DIM + f);
        acc.x += fmaxf(fmaf(xv.x, sc.x, sh.x) + ev.x, 0.f);
        acc.y += fmaxf(fmaf(xv.y, sc.y, sh.y) + ev.y, 0.f);
        acc.z += fmaxf(fmaf(xv.z, sc.z, sh.z) + ev.z, 0.f);
        acc.w += fmaxf(fmaf(xv.w, sc.w, sh.w) + ev.w, 0.f);
    }
    float4 xn = *(const float4*)(x + (size_t)n * DIM + f);
    float4 o;
    o.x = fmaf(xn.x, sc.x, sh.x) + acc.x;
    o.y = fmaf(xn.y, sc.y, sh.y) + acc.y;
    o.z = fmaf(xn.z, sc.z, sh.z) + acc.z;
    o.w = fmaf(xn.w, sc.w, sh.w) + acc.w;
    *(float4*)(sbuf + (size_t)n * DIM + f) = o;
}

// y[n][d] = relu(bias[d] + sum_k s[n][k] * W[d][k]); accumulate column sum/sumsq
__global__ __launch_bounds__(256) void gemm_k(
        const float* __restrict__ sbuf, const float* __restrict__ W,
        const float* __restrict__ bias, float* __restrict__ ybuf,
        double* __restrict__ gsum, double* __restrict__ gsumsq, int N) {
    __shared__ float Wt[DIM][DIM + 1];   // Wt[k][d] = W[d][k], padded: conflict-free
    __shared__ float sS[NB][DIM];
    __shared__ float red[2][DIM];
    __shared__ float redq[2][DIM];

    for (int idx = threadIdx.x; idx < DIM * DIM; idx += 256) {
        int d = idx >> 7, k = idx & 127;
        Wt[k][d] = W[idx];
    }
    int n0 = blockIdx.x * NB;
    for (int idx = threadIdx.x; idx < NB * DIM; idx += 256) {
        int i = idx >> 7, k = idx & 127;
        int n = n0 + i;
        sS[i][k] = (n < N) ? sbuf[(size_t)n * DIM + k] : 0.f;
    }
    __syncthreads();

    int d = threadIdx.x & 127;
    int g = threadIdx.x >> 7;    // 0 or 1; uniform per wave
    float acc[8];
#pragma unroll
    for (int j = 0; j < 8; ++j) acc[j] = 0.f;

    for (int k = 0; k < DIM; k += 4) {
        float w0 = Wt[k][d], w1 = Wt[k + 1][d], w2 = Wt[k + 2][d], w3 = Wt[k + 3][d];
#pragma unroll
        for (int j = 0; j < 8; ++j) {
            float4 s4 = *(const float4*)(&sS[j * 2 + g][k]);  // broadcast within wave
            acc[j] = fmaf(s4.x, w0, acc[j]);
            acc[j] = fmaf(s4.y, w1, acc[j]);
            acc[j] = fmaf(s4.z, w2, acc[j]);
            acc[j] = fmaf(s4.w, w3, acc[j]);
        }
    }

    float bd = bias[d];
    float lsum = 0.f, lsq = 0.f;
#pragma unroll
    for (int j = 0; j < 8; ++j) {
        int n = n0 + j * 2 + g;
        float y = fmaxf(acc[j] + bd, 0.f);
        if (n < N) {
            ybuf[(size_t)n * DIM + d] = y;
            lsum += y;
            lsq += y * y;
        }
    }
    red[g][d] = lsum;
    redq[g][d] = lsq;
    __syncthreads();
    if (g == 0) {
        float s2 = lsum + red[1][d];
        float q2 = lsq + redq[1][d];
        atomicAdd(&gsum[d], (double)s2);
        atomicAdd(&gsumsq[d], (double)q2);
    }
}

__global__ void finalize_k(const double* __restrict__ gsum, const double* __restrict__ gsumsq,
                           const float* __restrict__ gamma, const float* __restrict__ beta,
                           float* __restrict__ scale, float* __restrict__ shift) {
    int d = threadIdx.x;
    if (d < DIM) {
        double mean = gsum[d] * (1.0 / NN);
        double var = gsumsq[d] * (1.0 / NN) - mean * mean;
        float sc = gamma[d] * rsqrtf((float)var + BN_EPS);
        scale[d] = sc;
        shift[d] = beta[d] - (float)mean * sc;
    }
}

__global__ __launch_bounds__(256) void norm_out_k(
        const float* __restrict__ ybuf, const float* __restrict__ scale,
        const float* __restrict__ shift, float* __restrict__ out, int total4) {
    int i = blockIdx.x * 256 + threadIdx.x;
    if (i < total4) {
        int f = (i & 31) * 4;
        float4 y = ((const float4*)ybuf)[i];
        float4 sc = *(const float4*)(scale + f);
        float4 sh = *(const float4*)(shift + f);
        float4 o;
        o.x = fmaf(y.x, sc.x, sh.x);
        o.y = fmaf(y.y, sc.y, sh.y);
        o.z = fmaf(y.z, sc.z, sh.z);
        o.w = fmaf(y.w, sc.w, sh.w);
        ((float4*)out)[i] = o;
    }
}

// ---------------- launch ----------------

extern "C" void kernel_launch(void* const* d_in, const int* in_sizes, int n_in,
                              void* d_out, int out_size, void* d_ws, size_t ws_size,
                              hipStream_t stream) {
    const int* edge_index = (const int*)d_in[0];
    const int* srcs = edge_index;
    const int* dsts = edge_index + NE;
    const float* node_attr = (const float*)d_in[1];
    const float* eattr = (const float*)d_in[2];
    const float* Wp[3]    = {(const float*)d_in[3],  (const float*)d_in[7],  (const float*)d_in[11]};
    const float* bp[3]    = {(const float*)d_in[4],  (const float*)d_in[8],  (const float*)d_in[12]};
    const float* gammap[3]= {(const float*)d_in[5],  (const float*)d_in[9],  (const float*)d_in[13]};
    const float* betap[3] = {(const float*)d_in[6],  (const float*)d_in[10], (const float*)d_in[14]};

    char* ws = (char*)d_ws;
    float* ybuf = (float*)ws;                 ws += (size_t)NN * DIM * 4;
    int* eidx = (int*)ws;                     ws += (size_t)NE * 4;
    int* offsets = (int*)ws;                  ws += (size_t)(NN + 1) * 4;
    int* cursor = (int*)ws;                   ws += (size_t)NN * 4;
    int* counts = (int*)ws;                   ws += (size_t)NN * 4;
    ws = (char*)(((uintptr_t)ws + 15) & ~(uintptr_t)15);
    double* gsum = (double*)ws;               ws += DIM * 8;
    double* gsumsq = (double*)ws;             ws += DIM * 8;
    float* scaleA = (float*)ws;               ws += DIM * 4;
    float* shiftA = (float*)ws;               ws += DIM * 4;
    float* scaleB = (float*)ws;               ws += DIM * 4;
    float* shiftB = (float*)ws;               ws += DIM * 4;

    float* sbuf = (float*)d_out;   // reuse d_out as s = x + aggr scratch; fully rewritten at end

    // CSR build (once per call; reused by all 3 layers)
    hipMemsetAsync(counts, 0, (size_t)NN * 4, stream);
    count_k<<<(NE + 255) / 256, 256, 0, stream>>>(dsts, counts, NE);
    scan_k<<<1, 1024, 0, stream>>>(counts, offsets, cursor, NN);
    fill_k<<<(NE + 255) / 256, 256, 0, stream>>>(dsts, cursor, eidx, NE);
    ident_k<<<1, DIM, 0, stream>>>(scaleA, shiftA);

    const float* xcur = node_attr;
    float* sc = scaleA; float* sh = shiftA;
    float* scn = scaleB; float* shn = shiftB;
    for (int l = 0; l < 3; ++l) {
        aggregate_k<<<(NN + 7) / 8, 256, 0, stream>>>(xcur, sc, sh, eattr, srcs,
                                                      offsets, eidx, sbuf, NN);
        hipMemsetAsync(gsum, 0, DIM * 8 * 2, stream);  // gsum + gsumsq contiguous
        gemm_k<<<(NN + NB - 1) / NB, 256, 0, stream>>>(sbuf, Wp[l], bp[l], ybuf,
                                                       gsum, gsumsq, NN);
        finalize_k<<<1, DIM, 0, stream>>>(gsum, gsumsq, gammap[l], betap[l], scn, shn);
        xcur = ybuf;
        float* t;
        t = sc; sc = scn; scn = t;
        t = sh; sh = shn; shn = t;
    }
    norm_out_k<<<(NN * DIM / 4 + 255) / 256, 256, 0, stream>>>(ybuf, sc, sh,
                                                               (float*)d_out, NN * DIM / 4);
}

// Round 2
// 754.269 us; speedup vs baseline: 1.1871x; 1.1871x over previous
//
#include <hip/hip_runtime.h>
#include <stdint.h>

#define NN 50000
#define NE 600000
#define DIM 128
#define BN_EPS 1e-5f
#define NB 16                  // nodes per GEMM block
#define NCHUNK ((NN + 255) / 256)   // 196 scan chunks

// ---------------- CSR build ----------------

__global__ void count_k(const int* __restrict__ dst, int* __restrict__ counts, int E) {
    int i = blockIdx.x * 256 + threadIdx.x;
    if (i < E) atomicAdd(&counts[dst[i]], 1);
}

// per-256-chunk sums (196 blocks)
__global__ __launch_bounds__(256) void chunksum_k(const int* __restrict__ counts,
                                                  int* __restrict__ bsum) {
    __shared__ int lds[256];
    int i = blockIdx.x * 256 + threadIdx.x;
    lds[threadIdx.x] = (i < NN) ? counts[i] : 0;
    __syncthreads();
    for (int off = 128; off > 0; off >>= 1) {
        if (threadIdx.x < (unsigned)off) lds[threadIdx.x] += lds[threadIdx.x + off];
        __syncthreads();
    }
    if (threadIdx.x == 0) bsum[blockIdx.x] = lds[0];
}

// single block: exclusive-scan the 196 chunk sums; also init identity scale/shift
__global__ __launch_bounds__(256) void chunkscan_k(const int* __restrict__ bsum,
                                                   int* __restrict__ bbase,
                                                   int* __restrict__ offsets,
                                                   float* __restrict__ scaleA,
                                                   float* __restrict__ shiftA) {
    __shared__ int lds[256];
    int t = threadIdx.x;
    int v = (t < NCHUNK) ? bsum[t] : 0;
    lds[t] = v;
    __syncthreads();
    for (int off = 1; off < 256; off <<= 1) {
        int a = (t >= (unsigned)off) ? lds[t - off] : 0;
        __syncthreads();
        lds[t] += a;
        __syncthreads();
    }
    if (t < NCHUNK) bbase[t] = lds[t] - v;
    if (t == 0) offsets[NN] = NE;
    if (t < DIM) { scaleA[t] = 1.f; shiftA[t] = 0.f; }
}

// per-chunk local exclusive scan + chunk base -> offsets, cursor (196 blocks)
__global__ __launch_bounds__(256) void scatteroff_k(const int* __restrict__ counts,
                                                    const int* __restrict__ bbase,
                                                    int* __restrict__ offsets,
                                                    int* __restrict__ cursor) {
    __shared__ int lds[256];
    int t = threadIdx.x;
    int i = blockIdx.x * 256 + t;
    int v = (i < NN) ? counts[i] : 0;
    lds[t] = v;
    __syncthreads();
    for (int off = 1; off < 256; off <<= 1) {
        int a = (t >= (unsigned)off) ? lds[t - off] : 0;
        __syncthreads();
        lds[t] += a;
        __syncthreads();
    }
    if (i < NN) {
        int excl = bbase[blockIdx.x] + lds[t] - v;
        offsets[i] = excl;
        cursor[i] = excl;
    }
}

// scatter edge ids AND their source node ids into CSR order
__global__ void fill_k(const int* __restrict__ dst, const int* __restrict__ src,
                       int* __restrict__ cursor, int* __restrict__ eidx,
                       int* __restrict__ csrc, int E) {
    int i = blockIdx.x * 256 + threadIdx.x;
    if (i < E) {
        int p = atomicAdd(&cursor[dst[i]], 1);
        eidx[p] = i;
        csrc[p] = src[i];
    }
}

// ---------------- per-layer kernels ----------------

// s[n] = xnorm[n] + sum_{e: dst=n} relu(xnorm[src_e] + eattr[e]),
// xnorm = x*scale + shift (BN folded into reads).
// 256 threads = 8 nodes x 32 lanes; lane handles 4 features (float4).
// Edge indices are loaded 32-at-a-time coalesced (one per lane) and
// broadcast via shfl -> index fetches off the critical path, eattr/x
// loads independent across iterations.
__global__ __launch_bounds__(256) void aggregate_k(
        const float* __restrict__ x, const float* __restrict__ scale,
        const float* __restrict__ shift, const float* __restrict__ eattr,
        const int* __restrict__ offsets, const int* __restrict__ eidx,
        const int* __restrict__ csrc, float* __restrict__ sbuf, int N) {
    int lane = threadIdx.x & 31;
    int nloc = threadIdx.x >> 5;
    int n = blockIdx.x * 8 + nloc;
    if (n >= N) return;
    int f = lane * 4;
    const float* xf = x + f;
    const float* ef = eattr + f;
    float4 sc = *(const float4*)(scale + f);
    float4 sh = *(const float4*)(shift + f);
    float4 acc = make_float4(0.f, 0.f, 0.f, 0.f);
    int beg = offsets[n], end = offsets[n + 1];
    for (int base = beg; base < end; base += 32) {
        int kk = base + lane;
        int e_l = (kk < end) ? eidx[kk] : 0;
        int s_l = (kk < end) ? csrc[kk] : 0;
        int cnt = end - base;
        if (cnt > 32) cnt = 32;
#pragma unroll 4
        for (int t = 0; t < cnt; ++t) {
            int e = __shfl(e_l, t, 32);
            int s = __shfl(s_l, t, 32);
            float4 ev = *(const float4*)(ef + (size_t)e * DIM);
            float4 xv = *(const float4*)(xf + (size_t)s * DIM);
            acc.x += fmaxf(fmaf(xv.x, sc.x, sh.x) + ev.x, 0.f);
            acc.y += fmaxf(fmaf(xv.y, sc.y, sh.y) + ev.y, 0.f);
            acc.z += fmaxf(fmaf(xv.z, sc.z, sh.z) + ev.z, 0.f);
            acc.w += fmaxf(fmaf(xv.w, sc.w, sh.w) + ev.w, 0.f);
        }
    }
    float4 xn = *(const float4*)(xf + (size_t)n * DIM);
    float4 o;
    o.x = fmaf(xn.x, sc.x, sh.x) + acc.x;
    o.y = fmaf(xn.y, sc.y, sh.y) + acc.y;
    o.z = fmaf(xn.z, sc.z, sh.z) + acc.z;
    o.w = fmaf(xn.w, sc.w, sh.w) + acc.w;
    *(float4*)(sbuf + (size_t)n * DIM + f) = o;
}

// y[n][d] = relu(bias[d] + sum_k s[n][k] * W[d][k]); accumulate column sum/sumsq
__global__ __launch_bounds__(256) void gemm_k(
        const float* __restrict__ sbuf, const float* __restrict__ W,
        const float* __restrict__ bias, float* __restrict__ ybuf,
        double* __restrict__ gsum, double* __restrict__ gsumsq, int N) {
    __shared__ float Wt[DIM][DIM + 1];   // Wt[k][d] = W[d][k]
    __shared__ float sS[NB][DIM];
    __shared__ float red[2][DIM];
    __shared__ float redq[2][DIM];

    for (int idx = threadIdx.x; idx < DIM * DIM; idx += 256) {
        int d = idx >> 7, k = idx & 127;
        Wt[k][d] = W[idx];
    }
    int n0 = blockIdx.x * NB;
    for (int idx = threadIdx.x; idx < NB * DIM; idx += 256) {
        int i = idx >> 7, k = idx & 127;
        int n = n0 + i;
        sS[i][k] = (n < N) ? sbuf[(size_t)n * DIM + k] : 0.f;
    }
    __syncthreads();

    int d = threadIdx.x & 127;
    int g = threadIdx.x >> 7;    // 0 or 1; uniform per wave
    float acc[8];
#pragma unroll
    for (int j = 0; j < 8; ++j) acc[j] = 0.f;

    for (int k = 0; k < DIM; k += 4) {
        float w0 = Wt[k][d], w1 = Wt[k + 1][d], w2 = Wt[k + 2][d], w3 = Wt[k + 3][d];
#pragma unroll
        for (int j = 0; j < 8; ++j) {
            float4 s4 = *(const float4*)(&sS[j * 2 + g][k]);  // same-addr broadcast
            acc[j] = fmaf(s4.x, w0, acc[j]);
            acc[j] = fmaf(s4.y, w1, acc[j]);
            acc[j] = fmaf(s4.z, w2, acc[j]);
            acc[j] = fmaf(s4.w, w3, acc[j]);
        }
    }

    float bd = bias[d];
    float lsum = 0.f, lsq = 0.f;
#pragma unroll
    for (int j = 0; j < 8; ++j) {
        int n = n0 + j * 2 + g;
        float y = fmaxf(acc[j] + bd, 0.f);
        if (n < N) {
            ybuf[(size_t)n * DIM + d] = y;
            lsum += y;
            lsq += y * y;
        }
    }
    red[g][d] = lsum;
    redq[g][d] = lsq;
    __syncthreads();
    if (g == 0) {
        float s2 = lsum + red[1][d];
        float q2 = lsq + redq[1][d];
        atomicAdd(&gsum[d], (double)s2);
        atomicAdd(&gsumsq[d], (double)q2);
    }
}

// derive BN scale/shift; zero the accumulators for the next layer
__global__ void finalize_k(double* __restrict__ gsum, double* __restrict__ gsumsq,
                           const float* __restrict__ gamma, const float* __restrict__ beta,
                           float* __restrict__ scale, float* __restrict__ shift) {
    int d = threadIdx.x;
    if (d < DIM) {
        double mean = gsum[d] * (1.0 / NN);
        double var = gsumsq[d] * (1.0 / NN) - mean * mean;
        float sc = gamma[d] * rsqrtf((float)var + BN_EPS);
        scale[d] = sc;
        shift[d] = beta[d] - (float)mean * sc;
        gsum[d] = 0.0;
        gsumsq[d] = 0.0;
    }
}

__global__ __launch_bounds__(256) void norm_out_k(
        const float* __restrict__ ybuf, const float* __restrict__ scale,
        const float* __restrict__ shift, float* __restrict__ out, int total4) {
    int i = blockIdx.x * 256 + threadIdx.x;
    if (i < total4) {
        int f = (i & 31) * 4;
        float4 y = ((const float4*)ybuf)[i];
        float4 sc = *(const float4*)(scale + f);
        float4 sh = *(const float4*)(shift + f);
        float4 o;
        o.x = fmaf(y.x, sc.x, sh.x);
        o.y = fmaf(y.y, sc.y, sh.y);
        o.z = fmaf(y.z, sc.z, sh.z);
        o.w = fmaf(y.w, sc.w, sh.w);
        ((float4*)out)[i] = o;
    }
}

// ---------------- launch ----------------

extern "C" void kernel_launch(void* const* d_in, const int* in_sizes, int n_in,
                              void* d_out, int out_size, void* d_ws, size_t ws_size,
                              hipStream_t stream) {
    const int* edge_index = (const int*)d_in[0];
    const int* srcs = edge_index;
    const int* dsts = edge_index + NE;
    const float* node_attr = (const float*)d_in[1];
    const float* eattr = (const float*)d_in[2];
    const float* Wp[3]    = {(const float*)d_in[3],  (const float*)d_in[7],  (const float*)d_in[11]};
    const float* bp[3]    = {(const float*)d_in[4],  (const float*)d_in[8],  (const float*)d_in[12]};
    const float* gammap[3]= {(const float*)d_in[5],  (const float*)d_in[9],  (const float*)d_in[13]};
    const float* betap[3] = {(const float*)d_in[6],  (const float*)d_in[10], (const float*)d_in[14]};

    char* ws = (char*)d_ws;
    float* ybuf = (float*)ws;                 ws += (size_t)NN * DIM * 4;
    int* eidx = (int*)ws;                     ws += (size_t)NE * 4;
    int* csrc = (int*)ws;                     ws += (size_t)NE * 4;
    int* offsets = (int*)ws;                  ws += (size_t)(NN + 1) * 4;
    int* cursor = (int*)ws;                   ws += (size_t)NN * 4;
    int* bsum = (int*)ws;                     ws += (size_t)NCHUNK * 4;
    int* bbase = (int*)ws;                    ws += (size_t)NCHUNK * 4;
    ws = (char*)(((uintptr_t)ws + 15) & ~(uintptr_t)15);
    // contiguous zero-init region: counts | gsum | gsumsq
    int* counts = (int*)ws;                   ws += (size_t)NN * 4;
    double* gsum = (double*)ws;               ws += DIM * 8;
    double* gsumsq = (double*)ws;             ws += DIM * 8;
    float* scaleA = (float*)ws;               ws += DIM * 4;
    float* shiftA = (float*)ws;               ws += DIM * 4;
    float* scaleB = (float*)ws;               ws += DIM * 4;
    float* shiftB = (float*)ws;               ws += DIM * 4;

    float* sbuf = (float*)d_out;   // reuse d_out as s = x + aggr scratch

    // one memset covers counts + gsum + gsumsq (contiguous)
    hipMemsetAsync(counts, 0, (size_t)NN * 4 + 2 * DIM * 8, stream);
    count_k<<<(NE + 255) / 256, 256, 0, stream>>>(dsts, counts, NE);
    chunksum_k<<<NCHUNK, 256, 0, stream>>>(counts, bsum);
    chunkscan_k<<<1, 256, 0, stream>>>(bsum, bbase, offsets, scaleA, shiftA);
    scatteroff_k<<<NCHUNK, 256, 0, stream>>>(counts, bbase, offsets, cursor);
    fill_k<<<(NE + 255) / 256, 256, 0, stream>>>(dsts, srcs, cursor, eidx, csrc, NE);

    const float* xcur = node_attr;
    float* sc = scaleA; float* sh = shiftA;
    float* scn = scaleB; float* shn = shiftB;
    for (int l = 0; l < 3; ++l) {
        aggregate_k<<<(NN + 7) / 8, 256, 0, stream>>>(xcur, sc, sh, eattr, offsets,
                                                      eidx, csrc, sbuf, NN);
        gemm_k<<<(NN + NB - 1) / NB, 256, 0, stream>>>(sbuf, Wp[l], bp[l], ybuf,
                                                       gsum, gsumsq, NN);
        finalize_k<<<1, DIM, 0, stream>>>(gsum, gsumsq, gammap[l], betap[l], scn, shn);
        xcur = ybuf;
        float* t;
        t = sc; sc = scn; scn = t;
        t = sh; sh = shn; shn = t;
    }
    norm_out_k<<<(NN * DIM / 4 + 255) / 256, 256, 0, stream>>>(ybuf, sc, sh,
                                                               (float*)d_out, NN * DIM / 4);
}

// Round 3
// 544.274 us; speedup vs baseline: 1.6451x; 1.3858x over previous
//
#include <hip/hip_runtime.h>
#include <stdint.h>

#define NN 50000
#define NE 600000
#define DIM 128
#define BN_EPS 1e-5f
#define NCHUNK ((NN + 255) / 256)   // 196 scan chunks

typedef __attribute__((ext_vector_type(8))) short bf16x8;
typedef __attribute__((ext_vector_type(4))) float f32x4;

__device__ __forceinline__ unsigned short f2b(float f) {
    unsigned u = __float_as_uint(f);
    u += 0x7FFF + ((u >> 16) & 1);          // RNE
    return (unsigned short)(u >> 16);
}
__device__ __forceinline__ float b2f(unsigned short h) {
    return __uint_as_float((unsigned)h << 16);
}

// ---------------- CSR build ----------------

__global__ void count_k(const int* __restrict__ dst, int* __restrict__ counts, int E) {
    int i = blockIdx.x * 256 + threadIdx.x;
    if (i < E) atomicAdd(&counts[dst[i]], 1);
}

__global__ __launch_bounds__(256) void chunksum_k(const int* __restrict__ counts,
                                                  int* __restrict__ bsum) {
    __shared__ int lds[256];
    int i = blockIdx.x * 256 + threadIdx.x;
    lds[threadIdx.x] = (i < NN) ? counts[i] : 0;
    __syncthreads();
    for (int off = 128; off > 0; off >>= 1) {
        if (threadIdx.x < (unsigned)off) lds[threadIdx.x] += lds[threadIdx.x + off];
        __syncthreads();
    }
    if (threadIdx.x == 0) bsum[blockIdx.x] = lds[0];
}

__global__ __launch_bounds__(256) void chunkscan_k(const int* __restrict__ bsum,
                                                   int* __restrict__ bbase,
                                                   int* __restrict__ offsets) {
    __shared__ int lds[256];
    int t = threadIdx.x;
    int v = (t < NCHUNK) ? bsum[t] : 0;
    lds[t] = v;
    __syncthreads();
    for (int off = 1; off < 256; off <<= 1) {
        int a = (t >= (unsigned)off) ? lds[t - off] : 0;
        __syncthreads();
        lds[t] += a;
        __syncthreads();
    }
    if (t < NCHUNK) bbase[t] = lds[t] - v;
    if (t == 0) offsets[NN] = NE;
}

__global__ __launch_bounds__(256) void scatteroff_k(const int* __restrict__ counts,
                                                    const int* __restrict__ bbase,
                                                    int* __restrict__ offsets,
                                                    int* __restrict__ cursor) {
    __shared__ int lds[256];
    int t = threadIdx.x;
    int i = blockIdx.x * 256 + t;
    int v = (i < NN) ? counts[i] : 0;
    lds[t] = v;
    __syncthreads();
    for (int off = 1; off < 256; off <<= 1) {
        int a = (t >= (unsigned)off) ? lds[t - off] : 0;
        __syncthreads();
        lds[t] += a;
        __syncthreads();
    }
    if (i < NN) {
        int excl = bbase[blockIdx.x] + lds[t] - v;
        offsets[i] = excl;
        cursor[i] = excl;
    }
}

__global__ void fill_k(const int* __restrict__ dst, const int* __restrict__ src,
                       int* __restrict__ cursor, int* __restrict__ eidx,
                       int* __restrict__ csrc, int E) {
    int i = blockIdx.x * 256 + threadIdx.x;
    if (i < E) {
        int p = atomicAdd(&cursor[dst[i]], 1);
        eidx[p] = i;
        csrc[p] = src[i];
    }
}

// convert W1|W2|W3 (fp32 row-major [d][k]) to bf16
__global__ __launch_bounds__(256) void wcvt_k(const float* __restrict__ w0,
                                              const float* __restrict__ w1,
                                              const float* __restrict__ w2,
                                              unsigned short* __restrict__ out) {
    int i = blockIdx.x * 256 + threadIdx.x;   // [0, 3*4096)
    int which = i >> 12;
    int off = (i & 4095) * 4;
    const float* w = (which == 0) ? w0 : ((which == 1) ? w1 : w2);
    float4 v = *(const float4*)(w + off);
    ushort4 o = {f2b(v.x), f2b(v.y), f2b(v.z), f2b(v.w)};
    *(ushort4*)(out + (size_t)which * 16384 + off) = o;
}

// ---------------- layer kernels ----------------

// layer 1: s[n] = x[n] + sum relu(x[src]+e); x,eattr fp32; writes sbuf bf16;
// optionally writes CSR-ordered bf16 copy of eattr for layers 2-3.
template <bool WEBF>
__global__ __launch_bounds__(256) void agg1_k(
        const float* __restrict__ x, const float* __restrict__ eattr,
        const int* __restrict__ offsets, const int* __restrict__ eidx,
        const int* __restrict__ csrc, unsigned short* __restrict__ sb,
        unsigned short* __restrict__ ebf) {
    int lane = threadIdx.x & 31;
    int n = blockIdx.x * 8 + (threadIdx.x >> 5);
    int f = lane * 4;
    float4 acc = make_float4(0.f, 0.f, 0.f, 0.f);
    int beg = offsets[n], end = offsets[n + 1];
    for (int base = beg; base < end; base += 32) {
        int kk = base + lane;
        int e_l = (kk < end) ? eidx[kk] : 0;
        int s_l = (kk < end) ? csrc[kk] : 0;
        int cnt = end - base;
        if (cnt > 32) cnt = 32;
#pragma unroll 4
        for (int t = 0; t < cnt; ++t) {
            int e = __shfl(e_l, t, 32);
            int s = __shfl(s_l, t, 32);
            float4 ev = *(const float4*)(eattr + (size_t)e * DIM + f);
            float4 xv = *(const float4*)(x + (size_t)s * DIM + f);
            if (WEBF) {
                ushort4 eb = {f2b(ev.x), f2b(ev.y), f2b(ev.z), f2b(ev.w)};
                *(ushort4*)(ebf + (size_t)(base + t) * DIM + f) = eb;
            }
            acc.x += fmaxf(xv.x + ev.x, 0.f);
            acc.y += fmaxf(xv.y + ev.y, 0.f);
            acc.z += fmaxf(xv.z + ev.z, 0.f);
            acc.w += fmaxf(xv.w + ev.w, 0.f);
        }
    }
    float4 xn = *(const float4*)(x + (size_t)n * DIM + f);
    ushort4 o = {f2b(xn.x + acc.x), f2b(xn.y + acc.y),
                 f2b(xn.z + acc.z), f2b(xn.w + acc.w)};
    *(ushort4*)(sb + (size_t)n * DIM + f) = o;
}

// layers 2-3 (ebf path): x bf16 (pre-BN), BN folded via scale/shift; ebf streamed
// sequentially in CSR order (no eidx).
__global__ __launch_bounds__(256) void agg2_bf_k(
        const unsigned short* __restrict__ xb, const float* __restrict__ scale,
        const float* __restrict__ shift, const unsigned short* __restrict__ ebf,
        const int* __restrict__ offsets, const int* __restrict__ csrc,
        unsigned short* __restrict__ sb) {
    int lane = threadIdx.x & 31;
    int n = blockIdx.x * 8 + (threadIdx.x >> 5);
    int f = lane * 4;
    float4 sc = *(const float4*)(scale + f);
    float4 sh = *(const float4*)(shift + f);
    float4 acc = make_float4(0.f, 0.f, 0.f, 0.f);
    int beg = offsets[n], end = offsets[n + 1];
    for (int base = beg; base < end; base += 32) {
        int kk = base + lane;
        int s_l = (kk < end) ? csrc[kk] : 0;
        int cnt = end - base;
        if (cnt > 32) cnt = 32;
#pragma unroll 4
        for (int t = 0; t < cnt; ++t) {
            int s = __shfl(s_l, t, 32);
            ushort4 eb = *(const ushort4*)(ebf + (size_t)(base + t) * DIM + f);
            ushort4 xv = *(const ushort4*)(xb + (size_t)s * DIM + f);
            acc.x += fmaxf(fmaf(b2f(xv.x), sc.x, sh.x) + b2f(eb.x), 0.f);
            acc.y += fmaxf(fmaf(b2f(xv.y), sc.y, sh.y) + b2f(eb.y), 0.f);
            acc.z += fmaxf(fmaf(b2f(xv.z), sc.z, sh.z) + b2f(eb.z), 0.f);
            acc.w += fmaxf(fmaf(b2f(xv.w), sc.w, sh.w) + b2f(eb.w), 0.f);
        }
    }
    ushort4 xs = *(const ushort4*)(xb + (size_t)n * DIM + f);
    ushort4 o = {f2b(fmaf(b2f(xs.x), sc.x, sh.x) + acc.x),
                 f2b(fmaf(b2f(xs.y), sc.y, sh.y) + acc.y),
                 f2b(fmaf(b2f(xs.z), sc.z, sh.z) + acc.z),
                 f2b(fmaf(b2f(xs.w), sc.w, sh.w) + acc.w)};
    *(ushort4*)(sb + (size_t)n * DIM + f) = o;
}

// fallback (ws too small for ebf): fp32 eattr via eidx, x bf16
__global__ __launch_bounds__(256) void agg2_f32_k(
        const unsigned short* __restrict__ xb, const float* __restrict__ scale,
        const float* __restrict__ shift, const float* __restrict__ eattr,
        const int* __restrict__ offsets, const int* __restrict__ eidx,
        const int* __restrict__ csrc, unsigned short* __restrict__ sb) {
    int lane = threadIdx.x & 31;
    int n = blockIdx.x * 8 + (threadIdx.x >> 5);
    int f = lane * 4;
    float4 sc = *(const float4*)(scale + f);
    float4 sh = *(const float4*)(shift + f);
    float4 acc = make_float4(0.f, 0.f, 0.f, 0.f);
    int beg = offsets[n], end = offsets[n + 1];
    for (int base = beg; base < end; base += 32) {
        int kk = base + lane;
        int e_l = (kk < end) ? eidx[kk] : 0;
        int s_l = (kk < end) ? csrc[kk] : 0;
        int cnt = end - base;
        if (cnt > 32) cnt = 32;
#pragma unroll 4
        for (int t = 0; t < cnt; ++t) {
            int e = __shfl(e_l, t, 32);
            int s = __shfl(s_l, t, 32);
            float4 ev = *(const float4*)(eattr + (size_t)e * DIM + f);
            ushort4 xv = *(const ushort4*)(xb + (size_t)s * DIM + f);
            acc.x += fmaxf(fmaf(b2f(xv.x), sc.x, sh.x) + ev.x, 0.f);
            acc.y += fmaxf(fmaf(b2f(xv.y), sc.y, sh.y) + ev.y, 0.f);
            acc.z += fmaxf(fmaf(b2f(xv.z), sc.z, sh.z) + ev.z, 0.f);
            acc.w += fmaxf(fmaf(b2f(xv.w), sc.w, sh.w) + ev.w, 0.f);
        }
    }
    ushort4 xs = *(const ushort4*)(xb + (size_t)n * DIM + f);
    ushort4 o = {f2b(fmaf(b2f(xs.x), sc.x, sh.x) + acc.x),
                 f2b(fmaf(b2f(xs.y), sc.y, sh.y) + acc.y),
                 f2b(fmaf(b2f(xs.z), sc.z, sh.z) + acc.z),
                 f2b(fmaf(b2f(xs.w), sc.w, sh.w) + acc.w)};
    *(ushort4*)(sb + (size_t)n * DIM + f) = o;
}

// MFMA GEMM: y[n][d] = relu(bias[d] + sum_k s[n][k]*W[d][k]), bf16 in, bf16 out,
// fp32 accumulate; per-block 16 nodes x 128 dims; per-dim BN stats via f64 atomics.
// mfma_f32_16x16x32_bf16 layouts (learn_hip m89-verified):
//   A: row=lane&15, k=(lane>>4)*8+j   B: col=lane&15, k=(lane>>4)*8+j
//   C/D: col=lane&15, row=(lane>>4)*4+reg
__global__ __launch_bounds__(256) void gemm_k(
        const unsigned short* __restrict__ sb, const unsigned short* __restrict__ wb,
        const float* __restrict__ bias, unsigned short* __restrict__ yb,
        double* __restrict__ gsum, double* __restrict__ gsumsq) {
    __shared__ unsigned short ylds[16][136];
    int tid = threadIdx.x;
    int w = tid >> 6;
    int lane = tid & 63;
    int row = lane & 15;
    int kg = lane >> 4;
    int n0 = blockIdx.x * 16;
    int d0 = w * 32;

    const unsigned short* aptr = sb + (size_t)(n0 + row) * DIM + kg * 8;
    const unsigned short* bptr0 = wb + (size_t)(d0 + row) * DIM + kg * 8;
    const unsigned short* bptr1 = bptr0 + 16 * DIM;

    f32x4 acc0 = {0.f, 0.f, 0.f, 0.f};
    f32x4 acc1 = {0.f, 0.f, 0.f, 0.f};
#pragma unroll
    for (int ks = 0; ks < 4; ++ks) {
        bf16x8 a = *(const bf16x8*)(aptr + ks * 32);
        bf16x8 b0 = *(const bf16x8*)(bptr0 + ks * 32);
        bf16x8 b1 = *(const bf16x8*)(bptr1 + ks * 32);
        acc0 = __builtin_amdgcn_mfma_f32_16x16x32_bf16(a, b0, acc0, 0, 0, 0);
        acc1 = __builtin_amdgcn_mfma_f32_16x16x32_bf16(a, b1, acc1, 0, 0, 0);
    }

    float bias0 = bias[d0 + row];
    float bias1 = bias[d0 + 16 + row];
    float s0 = 0.f, q0 = 0.f, s1 = 0.f, q1 = 0.f;
#pragma unroll
    for (int r = 0; r < 4; ++r) {
        int m = kg * 4 + r;
        float y0 = fmaxf(acc0[r] + bias0, 0.f);
        float y1 = fmaxf(acc1[r] + bias1, 0.f);
        ylds[m][d0 + row] = f2b(y0);
        ylds[m][d0 + 16 + row] = f2b(y1);
        s0 += y0; q0 += y0 * y0;
        s1 += y1; q1 += y1 * y1;
    }
    s0 += __shfl_xor(s0, 16); s0 += __shfl_xor(s0, 32);
    q0 += __shfl_xor(q0, 16); q0 += __shfl_xor(q0, 32);
    s1 += __shfl_xor(s1, 16); s1 += __shfl_xor(s1, 32);
    q1 += __shfl_xor(q1, 16); q1 += __shfl_xor(q1, 32);
    if (kg == 0) {
        atomicAdd(&gsum[d0 + row], (double)s0);
        atomicAdd(&gsumsq[d0 + row], (double)q0);
        atomicAdd(&gsum[d0 + 16 + row], (double)s1);
        atomicAdd(&gsumsq[d0 + 16 + row], (double)q1);
    }
    __syncthreads();
    int nrow = tid >> 4, seg = tid & 15;
    *(float4*)(yb + (size_t)(n0 + nrow) * DIM + seg * 8) =
        *(const float4*)(&ylds[nrow][seg * 8]);
}

// derive BN scale/shift; zero stats for next layer
__global__ void finalize_k(double* __restrict__ gsum, double* __restrict__ gsumsq,
                           const float* __restrict__ gamma, const float* __restrict__ beta,
                           float* __restrict__ scale, float* __restrict__ shift) {
    int d = threadIdx.x;
    if (d < DIM) {
        double mean = gsum[d] * (1.0 / NN);
        double var = gsumsq[d] * (1.0 / NN) - mean * mean;
        float sc = gamma[d] * rsqrtf((float)var + BN_EPS);
        scale[d] = sc;
        shift[d] = beta[d] - (float)mean * sc;
        gsum[d] = 0.0;
        gsumsq[d] = 0.0;
    }
}

__global__ __launch_bounds__(256) void norm_out_k(
        const unsigned short* __restrict__ yb, const float* __restrict__ scale,
        const float* __restrict__ shift, float* __restrict__ out) {
    int i = blockIdx.x * 256 + threadIdx.x;   // [0, NN*DIM/4)
    int f = (i & 31) * 4;
    ushort4 y = *(const ushort4*)(yb + (size_t)i * 4);
    float4 sc = *(const float4*)(scale + f);
    float4 sh = *(const float4*)(shift + f);
    float4 o;
    o.x = fmaf(b2f(y.x), sc.x, sh.x);
    o.y = fmaf(b2f(y.y), sc.y, sh.y);
    o.z = fmaf(b2f(y.z), sc.z, sh.z);
    o.w = fmaf(b2f(y.w), sc.w, sh.w);
    ((float4*)out)[i] = o;
}

// ---------------- launch ----------------

extern "C" void kernel_launch(void* const* d_in, const int* in_sizes, int n_in,
                              void* d_out, int out_size, void* d_ws, size_t ws_size,
                              hipStream_t stream) {
    const int* edge_index = (const int*)d_in[0];
    const int* srcs = edge_index;
    const int* dsts = edge_index + NE;
    const float* node_attr = (const float*)d_in[1];
    const float* eattr = (const float*)d_in[2];
    const float* Wp[3]    = {(const float*)d_in[3],  (const float*)d_in[7],  (const float*)d_in[11]};
    const float* bp[3]    = {(const float*)d_in[4],  (const float*)d_in[8],  (const float*)d_in[12]};
    const float* gammap[3]= {(const float*)d_in[5],  (const float*)d_in[9],  (const float*)d_in[13]};
    const float* betap[3] = {(const float*)d_in[6],  (const float*)d_in[10], (const float*)d_in[14]};

    size_t off = 0;
    char* base = (char*)d_ws;
    auto carve = [&](size_t bytes) -> void* {
        void* p = base + off;
        off += (bytes + 255) & ~(size_t)255;
        return p;
    };
    unsigned short* ybuf = (unsigned short*)carve((size_t)NN * DIM * 2);
    int* eidx    = (int*)carve((size_t)NE * 4);
    int* csrc    = (int*)carve((size_t)NE * 4);
    int* offsets = (int*)carve((size_t)(NN + 1) * 4);
    int* cursor  = (int*)carve((size_t)NN * 4);
    int* bsum    = (int*)carve((size_t)NCHUNK * 4);
    int* bbase   = (int*)carve((size_t)NCHUNK * 4);
    // contiguous zero region: counts | gsum | gsumsq (each 256-padded, adjacent)
    int* counts  = (int*)carve((size_t)NN * 4);            // 200192 padded
    double* gsum = (double*)carve(DIM * 8);                // 1024
    double* gsumsq = (double*)carve(DIM * 8);              // 1024
    size_t zero_bytes = (size_t)((char*)gsumsq - (char*)counts) + DIM * 8;
    float* scb   = (float*)carve(3 * DIM * 4);             // scale[3][128]
    float* shb   = (float*)carve(3 * DIM * 4);             // shift[3][128]
    unsigned short* wb = (unsigned short*)carve(3 * DIM * DIM * 2);
    int use_ebf = (off + (size_t)NE * DIM * 2 <= ws_size);
    unsigned short* ebf = use_ebf ? (unsigned short*)carve((size_t)NE * DIM * 2) : nullptr;

    unsigned short* sbuf = (unsigned short*)d_out;  // bf16 s-scratch inside d_out

    hipMemsetAsync(counts, 0, zero_bytes, stream);
    count_k<<<(NE + 255) / 256, 256, 0, stream>>>(dsts, counts, NE);
    chunksum_k<<<NCHUNK, 256, 0, stream>>>(counts, bsum);
    chunkscan_k<<<1, 256, 0, stream>>>(bsum, bbase, offsets);
    scatteroff_k<<<NCHUNK, 256, 0, stream>>>(counts, bbase, offsets, cursor);
    fill_k<<<(NE + 255) / 256, 256, 0, stream>>>(dsts, srcs, cursor, eidx, csrc, NE);
    wcvt_k<<<48, 256, 0, stream>>>(Wp[0], Wp[1], Wp[2], wb);

    // ---- layer 1 ----
    if (use_ebf)
        agg1_k<true><<<NN / 8, 256, 0, stream>>>(node_attr, eattr, offsets, eidx, csrc, sbuf, ebf);
    else
        agg1_k<false><<<NN / 8, 256, 0, stream>>>(node_attr, eattr, offsets, eidx, csrc, sbuf, nullptr);
    gemm_k<<<NN / 16, 256, 0, stream>>>(sbuf, wb, bp[0], ybuf, gsum, gsumsq);
    finalize_k<<<1, DIM, 0, stream>>>(gsum, gsumsq, gammap[0], betap[0], scb, shb);

    // ---- layers 2,3 ----
    for (int l = 1; l < 3; ++l) {
        const float* sc = scb + (l - 1) * DIM;
        const float* sh = shb + (l - 1) * DIM;
        if (use_ebf)
            agg2_bf_k<<<NN / 8, 256, 0, stream>>>(ybuf, sc, sh, ebf, offsets, csrc, sbuf);
        else
            agg2_f32_k<<<NN / 8, 256, 0, stream>>>(ybuf, sc, sh, eattr, offsets, eidx, csrc, sbuf);
        gemm_k<<<NN / 16, 256, 0, stream>>>(sbuf, wb + l * DIM * DIM, bp[l], ybuf, gsum, gsumsq);
        finalize_k<<<1, DIM, 0, stream>>>(gsum, gsumsq, gammap[l], betap[l],
                                          scb + l * DIM, shb + l * DIM);
    }
    norm_out_k<<<NN * DIM / 4 / 256, 256, 0, stream>>>(ybuf, scb + 2 * DIM, shb + 2 * DIM,
                                                       (float*)d_out);
}

// Round 5
// 498.016 us; speedup vs baseline: 1.7979x; 1.0929x over previous
//
#include <hip/hip_runtime.h>
#include <stdint.h>

#define NN 50000
#define NE 600000
#define DIM 128
#define BN_EPS 1e-5f
#define NCHUNK ((NN + 255) / 256)   // 196 scan chunks

typedef __attribute__((ext_vector_type(8))) short bf16x8;
typedef __attribute__((ext_vector_type(4))) float f32x4;

__device__ __forceinline__ unsigned short f2b(float f) {
    unsigned u = __float_as_uint(f);
    u += 0x7FFF + ((u >> 16) & 1);          // RNE
    return (unsigned short)(u >> 16);
}
__device__ __forceinline__ float b2f(unsigned short h) {
    return __uint_as_float((unsigned)h << 16);
}

// ---------------- CSR build ----------------

__global__ void count_k(const int* __restrict__ dst, int* __restrict__ counts, int E) {
    int i = blockIdx.x * 256 + threadIdx.x;
    if (i < E) atomicAdd(&counts[dst[i]], 1);
}

__global__ __launch_bounds__(256) void chunksum_k(const int* __restrict__ counts,
                                                  int* __restrict__ bsum) {
    __shared__ int lds[256];
    int i = blockIdx.x * 256 + threadIdx.x;
    lds[threadIdx.x] = (i < NN) ? counts[i] : 0;
    __syncthreads();
    for (int off = 128; off > 0; off >>= 1) {
        if (threadIdx.x < (unsigned)off) lds[threadIdx.x] += lds[threadIdx.x + off];
        __syncthreads();
    }
    if (threadIdx.x == 0) bsum[blockIdx.x] = lds[0];
}

__global__ __launch_bounds__(256) void chunkscan_k(const int* __restrict__ bsum,
                                                   int* __restrict__ bbase,
                                                   int* __restrict__ offsets) {
    __shared__ int lds[256];
    int t = threadIdx.x;
    int v = (t < NCHUNK) ? bsum[t] : 0;
    lds[t] = v;
    __syncthreads();
    for (int off = 1; off < 256; off <<= 1) {
        int a = (t >= (unsigned)off) ? lds[t - off] : 0;
        __syncthreads();
        lds[t] += a;
        __syncthreads();
    }
    if (t < NCHUNK) bbase[t] = lds[t] - v;
    if (t == 0) offsets[NN] = NE;
}

__global__ __launch_bounds__(256) void scatteroff_k(const int* __restrict__ counts,
                                                    const int* __restrict__ bbase,
                                                    int* __restrict__ offsets,
                                                    int* __restrict__ cursor) {
    __shared__ int lds[256];
    int t = threadIdx.x;
    int i = blockIdx.x * 256 + t;
    int v = (i < NN) ? counts[i] : 0;
    lds[t] = v;
    __syncthreads();
    for (int off = 1; off < 256; off <<= 1) {
        int a = (t >= (unsigned)off) ? lds[t - off] : 0;
        __syncthreads();
        lds[t] += a;
        __syncthreads();
    }
    if (i < NN) {
        int excl = bbase[blockIdx.x] + lds[t] - v;
        offsets[i] = excl;
        cursor[i] = excl;
    }
}

// CSR fill + sequential-streaming eattr -> CSR-ordered bf16 copy.
// 256 threads = 8 groups x 32 lanes; each group owns 32 consecutive edges.
template <bool WEBF>
__global__ __launch_bounds__(256) void fillcvt_k(
        const int* __restrict__ dst, const int* __restrict__ src,
        const float* __restrict__ eattr, int* __restrict__ cursor,
        int* __restrict__ csrc, int* __restrict__ eidx,
        unsigned short* __restrict__ ebf) {
    int lane = threadIdx.x & 31;
    int g = blockIdx.x * 8 + (threadIdx.x >> 5);
    int base = g * 32;
    if (base >= NE) return;                 // NE % 32 == 0: full groups only
    int i = base + lane;
    int d = dst[i];
    int p = atomicAdd(&cursor[d], 1);
    csrc[p] = src[i];
    eidx[p] = i;
    if (!WEBF) return;
    int f = lane * 4;
    for (int t = 0; t < 32; ++t) {
        int pt = __shfl(p, t, 32);
        float4 v = *(const float4*)(eattr + (size_t)(base + t) * DIM + f);
        ushort4 o = {f2b(v.x), f2b(v.y), f2b(v.z), f2b(v.w)};
        *(ushort4*)(ebf + (size_t)pt * DIM + f) = o;
    }
}

// split W (fp32 row-major [d][k]) into bf16 hi + lo parts
__global__ __launch_bounds__(256) void wcvt_k(const float* __restrict__ w0,
                                              const float* __restrict__ w1,
                                              const float* __restrict__ w2,
                                              unsigned short* __restrict__ whi,
                                              unsigned short* __restrict__ wlo) {
    int i = blockIdx.x * 256 + threadIdx.x;   // [0, 3*4096)
    int which = i >> 12;
    int off = (i & 4095) * 4;
    const float* w = (which == 0) ? w0 : ((which == 1) ? w1 : w2);
    float4 v = *(const float4*)(w + off);
    ushort4 h = {f2b(v.x), f2b(v.y), f2b(v.z), f2b(v.w)};
    ushort4 l = {f2b(v.x - b2f(h.x)), f2b(v.y - b2f(h.y)),
                 f2b(v.z - b2f(h.z)), f2b(v.w - b2f(h.w))};
    *(ushort4*)(whi + (size_t)which * 16384 + off) = h;
    *(ushort4*)(wlo + (size_t)which * 16384 + off) = l;
}

// ---------------- fused layer kernel ----------------
// Per block: 16 nodes. Phase A: aggregate into fp32 LDS. Phase B: split-bf16
// MFMA GEMM + BN stats. xin and yout MUST be distinct buffers (inter-block
// gather of xin races with yout writes otherwise -> ping-pong in launcher).
// XMODE: 0 = x fp32 identity (layer 1), 1 = x bf16 with scale/shift.
// EMODE: 0 = sequential bf16 ebf, 1 = fallback fp32 eattr via eidx.
template <int XMODE, int EMODE>
__global__ __launch_bounds__(256) void layer_k(
        const float* __restrict__ xf, const unsigned short* __restrict__ xb,
        const float* __restrict__ scale, const float* __restrict__ shift,
        const unsigned short* __restrict__ ebf, const float* __restrict__ eattr,
        const int* __restrict__ eidx, const int* __restrict__ offsets,
        const int* __restrict__ csrc,
        const unsigned short* __restrict__ whi, const unsigned short* __restrict__ wlo,
        const float* __restrict__ bias, unsigned short* __restrict__ yb,
        double* __restrict__ gsum, double* __restrict__ gsumsq) {
    __shared__ float sS[16][DIM + 4];        // stride 528B: 2-way bank alias only
    __shared__ unsigned short ylds[16][136];

    int tid = threadIdx.x;
    int lane31 = tid & 31;
    int grp = tid >> 5;
    int n0 = blockIdx.x * 16;
    int f = lane31 * 4;

    float4 sc, sh;
    if (XMODE) {
        sc = *(const float4*)(scale + f);
        sh = *(const float4*)(shift + f);
    }

#pragma unroll
    for (int sub = 0; sub < 2; ++sub) {
        int n = n0 + grp * 2 + sub;
        float4 acc = make_float4(0.f, 0.f, 0.f, 0.f);
        int beg = offsets[n], end = offsets[n + 1];
        for (int b = beg; b < end; b += 32) {
            int kk = b + lane31;
            int s_l = (kk < end) ? csrc[kk] : 0;
            int e_l = 0;
            if (EMODE == 1) e_l = (kk < end) ? eidx[kk] : 0;
            int cnt = end - b;
            if (cnt > 32) cnt = 32;
#pragma unroll 4
            for (int t = 0; t < cnt; ++t) {
                int s = __shfl(s_l, t, 32);
                float4 ev;
                if (EMODE == 0) {
                    ushort4 eb = *(const ushort4*)(ebf + (size_t)(b + t) * DIM + f);
                    ev = make_float4(b2f(eb.x), b2f(eb.y), b2f(eb.z), b2f(eb.w));
                } else {
                    int e = __shfl(e_l, t, 32);
                    ev = *(const float4*)(eattr + (size_t)e * DIM + f);
                }
                float4 xv;
                if (XMODE == 0) {
                    xv = *(const float4*)(xf + (size_t)s * DIM + f);
                } else {
                    ushort4 u = *(const ushort4*)(xb + (size_t)s * DIM + f);
                    xv = make_float4(fmaf(b2f(u.x), sc.x, sh.x),
                                     fmaf(b2f(u.y), sc.y, sh.y),
                                     fmaf(b2f(u.z), sc.z, sh.z),
                                     fmaf(b2f(u.w), sc.w, sh.w));
                }
                acc.x += fmaxf(xv.x + ev.x, 0.f);
                acc.y += fmaxf(xv.y + ev.y, 0.f);
                acc.z += fmaxf(xv.z + ev.z, 0.f);
                acc.w += fmaxf(xv.w + ev.w, 0.f);
            }
        }
        float4 xn;
        if (XMODE == 0) {
            xn = *(const float4*)(xf + (size_t)n * DIM + f);
        } else {
            ushort4 u = *(const ushort4*)(xb + (size_t)n * DIM + f);
            xn = make_float4(fmaf(b2f(u.x), sc.x, sh.x), fmaf(b2f(u.y), sc.y, sh.y),
                             fmaf(b2f(u.z), sc.z, sh.z), fmaf(b2f(u.w), sc.w, sh.w));
        }
        float4 o = make_float4(xn.x + acc.x, xn.y + acc.y, xn.z + acc.z, xn.w + acc.w);
        *(float4*)(&sS[grp * 2 + sub][f]) = o;
    }
    __syncthreads();

    // ---- GEMM phase ----
    int wv = tid >> 6;
    int lane = tid & 63;
    int row = lane & 15;      // A row (node) / B col (dim)
    int kg = lane >> 4;       // k-group
    int d0 = wv * 32;
    const unsigned short* bh = whi + (size_t)(d0 + row) * DIM + kg * 8;
    const unsigned short* bl = wlo + (size_t)(d0 + row) * DIM + kg * 8;

    f32x4 acc0 = {0.f, 0.f, 0.f, 0.f};
    f32x4 acc1 = {0.f, 0.f, 0.f, 0.f};
#pragma unroll
    for (int ks = 0; ks < 4; ++ks) {
        const float* ap = &sS[row][kg * 8 + ks * 32];
        bf16x8 ahi, alo;
#pragma unroll
        for (int j = 0; j < 8; ++j) {
            float av = ap[j];
            unsigned short h = f2b(av);
            ahi[j] = (short)h;
            alo[j] = (short)f2b(av - b2f(h));
        }
        bf16x8 b0h = *(const bf16x8*)(bh + ks * 32);
        bf16x8 b0l = *(const bf16x8*)(bl + ks * 32);
        bf16x8 b1h = *(const bf16x8*)(bh + 16 * DIM + ks * 32);
        bf16x8 b1l = *(const bf16x8*)(bl + 16 * DIM + ks * 32);
        acc0 = __builtin_amdgcn_mfma_f32_16x16x32_bf16(ahi, b0h, acc0, 0, 0, 0);
        acc0 = __builtin_amdgcn_mfma_f32_16x16x32_bf16(ahi, b0l, acc0, 0, 0, 0);
        acc0 = __builtin_amdgcn_mfma_f32_16x16x32_bf16(alo, b0h, acc0, 0, 0, 0);
        acc1 = __builtin_amdgcn_mfma_f32_16x16x32_bf16(ahi, b1h, acc1, 0, 0, 0);
        acc1 = __builtin_amdgcn_mfma_f32_16x16x32_bf16(ahi, b1l, acc1, 0, 0, 0);
        acc1 = __builtin_amdgcn_mfma_f32_16x16x32_bf16(alo, b1h, acc1, 0, 0, 0);
    }

    float bias0 = bias[d0 + row];
    float bias1 = bias[d0 + 16 + row];
    float s0 = 0.f, q0 = 0.f, s1 = 0.f, q1 = 0.f;
#pragma unroll
    for (int r = 0; r < 4; ++r) {
        int m = kg * 4 + r;
        float y0 = fmaxf(acc0[r] + bias0, 0.f);
        float y1 = fmaxf(acc1[r] + bias1, 0.f);
        ylds[m][d0 + row] = f2b(y0);
        ylds[m][d0 + 16 + row] = f2b(y1);
        s0 += y0; q0 += y0 * y0;
        s1 += y1; q1 += y1 * y1;
    }
    s0 += __shfl_xor(s0, 16); s0 += __shfl_xor(s0, 32);
    q0 += __shfl_xor(q0, 16); q0 += __shfl_xor(q0, 32);
    s1 += __shfl_xor(s1, 16); s1 += __shfl_xor(s1, 32);
    q1 += __shfl_xor(q1, 16); q1 += __shfl_xor(q1, 32);
    if (kg == 0) {
        atomicAdd(&gsum[d0 + row], (double)s0);
        atomicAdd(&gsumsq[d0 + row], (double)q0);
        atomicAdd(&gsum[d0 + 16 + row], (double)s1);
        atomicAdd(&gsumsq[d0 + 16 + row], (double)q1);
    }
    __syncthreads();
    int nrow = tid >> 4, seg = tid & 15;
    *(float4*)(yb + (size_t)(n0 + nrow) * DIM + seg * 8) =
        *(const float4*)(&ylds[nrow][seg * 8]);
}

// derive BN scale/shift; zero stats for next layer
__global__ void finalize_k(double* __restrict__ gsum, double* __restrict__ gsumsq,
                           const float* __restrict__ gamma, const float* __restrict__ beta,
                           float* __restrict__ scale, float* __restrict__ shift) {
    int d = threadIdx.x;
    if (d < DIM) {
        double mean = gsum[d] * (1.0 / NN);
        double var = gsumsq[d] * (1.0 / NN) - mean * mean;
        float sc = gamma[d] * rsqrtf((float)var + BN_EPS);
        scale[d] = sc;
        shift[d] = beta[d] - (float)mean * sc;
        gsum[d] = 0.0;
        gsumsq[d] = 0.0;
    }
}

__global__ __launch_bounds__(256) void norm_out_k(
        const unsigned short* __restrict__ yb, const float* __restrict__ scale,
        const float* __restrict__ shift, float* __restrict__ out) {
    int i = blockIdx.x * 256 + threadIdx.x;   // [0, NN*DIM/4)
    int f = (i & 31) * 4;
    ushort4 y = *(const ushort4*)(yb + (size_t)i * 4);
    float4 sc = *(const float4*)(scale + f);
    float4 sh = *(const float4*)(shift + f);
    float4 o;
    o.x = fmaf(b2f(y.x), sc.x, sh.x);
    o.y = fmaf(b2f(y.y), sc.y, sh.y);
    o.z = fmaf(b2f(y.z), sc.z, sh.z);
    o.w = fmaf(b2f(y.w), sc.w, sh.w);
    ((float4*)out)[i] = o;
}

// ---------------- launch ----------------

extern "C" void kernel_launch(void* const* d_in, const int* in_sizes, int n_in,
                              void* d_out, int out_size, void* d_ws, size_t ws_size,
                              hipStream_t stream) {
    const int* edge_index = (const int*)d_in[0];
    const int* srcs = edge_index;
    const int* dsts = edge_index + NE;
    const float* node_attr = (const float*)d_in[1];
    const float* eattr = (const float*)d_in[2];
    const float* Wp[3]    = {(const float*)d_in[3],  (const float*)d_in[7],  (const float*)d_in[11]};
    const float* bp[3]    = {(const float*)d_in[4],  (const float*)d_in[8],  (const float*)d_in[12]};
    const float* gammap[3]= {(const float*)d_in[5],  (const float*)d_in[9],  (const float*)d_in[13]};
    const float* betap[3] = {(const float*)d_in[6],  (const float*)d_in[10], (const float*)d_in[14]};

    size_t off = 0;
    char* base = (char*)d_ws;
    auto carve = [&](size_t bytes) -> void* {
        void* p = base + off;
        off += (bytes + 255) & ~(size_t)255;
        return p;
    };
    unsigned short* ybufA = (unsigned short*)carve((size_t)NN * DIM * 2);
    unsigned short* ybufB = (unsigned short*)carve((size_t)NN * DIM * 2);
    int* csrc    = (int*)carve((size_t)NE * 4);
    int* eidx    = (int*)carve((size_t)NE * 4);
    int* offsets = (int*)carve((size_t)(NN + 1) * 4);
    int* cursor  = (int*)carve((size_t)NN * 4);
    int* bsum    = (int*)carve((size_t)NCHUNK * 4);
    int* bbase   = (int*)carve((size_t)NCHUNK * 4);
    // contiguous zero region: counts | gsum | gsumsq
    int* counts  = (int*)carve((size_t)NN * 4);
    double* gsum = (double*)carve(DIM * 8);
    double* gsumsq = (double*)carve(DIM * 8);
    size_t zero_bytes = (size_t)((char*)gsumsq - (char*)counts) + DIM * 8;
    float* scb   = (float*)carve(3 * DIM * 4);
    float* shb   = (float*)carve(3 * DIM * 4);
    unsigned short* whi = (unsigned short*)carve(3 * DIM * DIM * 2);
    unsigned short* wlo = (unsigned short*)carve(3 * DIM * DIM * 2);
    int use_ebf = (off + (size_t)NE * DIM * 2 <= ws_size);
    unsigned short* ebf = use_ebf ? (unsigned short*)carve((size_t)NE * DIM * 2) : nullptr;

    hipMemsetAsync(counts, 0, zero_bytes, stream);
    count_k<<<(NE + 255) / 256, 256, 0, stream>>>(dsts, counts, NE);
    chunksum_k<<<NCHUNK, 256, 0, stream>>>(counts, bsum);
    chunkscan_k<<<1, 256, 0, stream>>>(bsum, bbase, offsets);
    scatteroff_k<<<NCHUNK, 256, 0, stream>>>(counts, bbase, offsets, cursor);
    if (use_ebf)
        fillcvt_k<true><<<(NE / 32 + 7) / 8, 256, 0, stream>>>(dsts, srcs, eattr, cursor,
                                                               csrc, eidx, ebf);
    else
        fillcvt_k<false><<<(NE / 32 + 7) / 8, 256, 0, stream>>>(dsts, srcs, eattr, cursor,
                                                                csrc, eidx, nullptr);
    wcvt_k<<<48, 256, 0, stream>>>(Wp[0], Wp[1], Wp[2], whi, wlo);

    // ---- layer 1: node_attr -> ybufA ----
    if (use_ebf)
        layer_k<0, 0><<<NN / 16, 256, 0, stream>>>(node_attr, nullptr, nullptr, nullptr,
                                                   ebf, eattr, eidx, offsets, csrc,
                                                   whi, wlo, bp[0], ybufA, gsum, gsumsq);
    else
        layer_k<0, 1><<<NN / 16, 256, 0, stream>>>(node_attr, nullptr, nullptr, nullptr,
                                                   nullptr, eattr, eidx, offsets, csrc,
                                                   whi, wlo, bp[0], ybufA, gsum, gsumsq);
    finalize_k<<<1, DIM, 0, stream>>>(gsum, gsumsq, gammap[0], betap[0], scb, shb);

    // ---- layers 2,3: ping-pong A->B->A (gather input must not alias output) ----
    unsigned short* xin = ybufA;
    unsigned short* yout = ybufB;
    for (int l = 1; l < 3; ++l) {
        const float* sc = scb + (l - 1) * DIM;
        const float* sh = shb + (l - 1) * DIM;
        if (use_ebf)
            layer_k<1, 0><<<NN / 16, 256, 0, stream>>>(nullptr, xin, sc, sh,
                                                       ebf, eattr, eidx, offsets, csrc,
                                                       whi + l * DIM * DIM, wlo + l * DIM * DIM,
                                                       bp[l], yout, gsum, gsumsq);
        else
            layer_k<1, 1><<<NN / 16, 256, 0, stream>>>(nullptr, xin, sc, sh,
                                                       nullptr, eattr, eidx, offsets, csrc,
                                                       whi + l * DIM * DIM, wlo + l * DIM * DIM,
                                                       bp[l], yout, gsum, gsumsq);
        finalize_k<<<1, DIM, 0, stream>>>(gsum, gsumsq, gammap[l], betap[l],
                                          scb + l * DIM, shb + l * DIM);
        unsigned short* t = xin; xin = yout; yout = t;
    }
    // final layer output is in xin (== ybufA after two swaps)
    norm_out_k<<<NN * DIM / 4 / 256, 256, 0, stream>>>(xin, scb + 2 * DIM, shb + 2 * DIM,
                                                       (float*)d_out);
}

// Round 8
// 491.803 us; speedup vs baseline: 1.8206x; 1.0126x over previous
//
#include <hip/hip_runtime.h>
#include <stdint.h>

#define NN 50000
#define NE 600000
#define DIM 128
#define BN_EPS 1e-5f
#define NCHUNK ((NN + 255) / 256)   // 196 scan chunks

typedef __attribute__((ext_vector_type(8))) short bf16x8;
typedef __attribute__((ext_vector_type(4))) float f32x4;

__device__ __forceinline__ unsigned short f2b(float f) {
    unsigned u = __float_as_uint(f);
    u += 0x7FFF + ((u >> 16) & 1);          // RNE
    return (unsigned short)(u >> 16);
}
__device__ __forceinline__ float b2f(unsigned short h) {
    return __uint_as_float((unsigned)h << 16);
}

// ---------------- CSR build ----------------

// zero counts + BN stat accumulators (replaces hipMemsetAsync — the captured
// fill node showed ~180us for a 197KB fill, 3x in the graph)
__global__ __launch_bounds__(256) void zero_k(int* __restrict__ counts,
                                              double* __restrict__ gsum,
                                              double* __restrict__ gsumsq) {
    int i = blockIdx.x * 256 + threadIdx.x;
    if (i < NN) counts[i] = 0;
    if (i < DIM) { gsum[i] = 0.0; gsumsq[i] = 0.0; }
}

__global__ void count_k(const int* __restrict__ dst, int* __restrict__ counts, int E) {
    int i = blockIdx.x * 256 + threadIdx.x;
    if (i < E) atomicAdd(&counts[dst[i]], 1);
}

__global__ __launch_bounds__(256) void chunksum_k(const int* __restrict__ counts,
                                                  int* __restrict__ bsum) {
    __shared__ int lds[256];
    int i = blockIdx.x * 256 + threadIdx.x;
    lds[threadIdx.x] = (i < NN) ? counts[i] : 0;
    __syncthreads();
    for (int off = 128; off > 0; off >>= 1) {
        if (threadIdx.x < (unsigned)off) lds[threadIdx.x] += lds[threadIdx.x + off];
        __syncthreads();
    }
    if (threadIdx.x == 0) bsum[blockIdx.x] = lds[0];
}

__global__ __launch_bounds__(256) void chunkscan_k(const int* __restrict__ bsum,
                                                   int* __restrict__ bbase,
                                                   int* __restrict__ offsets) {
    __shared__ int lds[256];
    int t = threadIdx.x;
    int v = (t < NCHUNK) ? bsum[t] : 0;
    lds[t] = v;
    __syncthreads();
    for (int off = 1; off < 256; off <<= 1) {
        int a = (t >= (unsigned)off) ? lds[t - off] : 0;
        __syncthreads();
        lds[t] += a;
        __syncthreads();
    }
    if (t < NCHUNK) bbase[t] = lds[t] - v;
    if (t == 0) offsets[NN] = NE;
}

__global__ __launch_bounds__(256) void scatteroff_k(const int* __restrict__ counts,
                                                    const int* __restrict__ bbase,
                                                    int* __restrict__ offsets,
                                                    int* __restrict__ cursor) {
    __shared__ int lds[256];
    int t = threadIdx.x;
    int i = blockIdx.x * 256 + t;
    int v = (i < NN) ? counts[i] : 0;
    lds[t] = v;
    __syncthreads();
    for (int off = 1; off < 256; off <<= 1) {
        int a = (t >= (unsigned)off) ? lds[t - off] : 0;
        __syncthreads();
        lds[t] += a;
        __syncthreads();
    }
    if (i < NN) {
        int excl = bbase[blockIdx.x] + lds[t] - v;
        offsets[i] = excl;
        cursor[i] = excl;
    }
}

// CSR fill + sequential-streaming eattr -> CSR-ordered bf16 copy.
// 256 threads = 8 groups x 32 lanes; each group owns 32 consecutive edges.
template <bool WEBF>
__global__ __launch_bounds__(256) void fillcvt_k(
        const int* __restrict__ dst, const int* __restrict__ src,
        const float* __restrict__ eattr, int* __restrict__ cursor,
        int* __restrict__ csrc, int* __restrict__ eidx,
        unsigned short* __restrict__ ebf) {
    int lane = threadIdx.x & 31;
    int g = blockIdx.x * 8 + (threadIdx.x >> 5);
    int base = g * 32;
    if (base >= NE) return;                 // NE % 32 == 0: full groups only
    int i = base + lane;
    int d = dst[i];
    int p = atomicAdd(&cursor[d], 1);
    csrc[p] = src[i];
    if (!WEBF) { eidx[p] = i; return; }
    int f = lane * 4;
    for (int t = 0; t < 32; ++t) {
        int pt = __shfl(p, t, 32);
        float4 v = *(const float4*)(eattr + (size_t)(base + t) * DIM + f);
        ushort4 o = {f2b(v.x), f2b(v.y), f2b(v.z), f2b(v.w)};
        *(ushort4*)(ebf + (size_t)pt * DIM + f) = o;
    }
}

// split W (fp32 row-major [d][k]) into bf16 hi + lo parts
__global__ __launch_bounds__(256) void wcvt_k(const float* __restrict__ w0,
                                              const float* __restrict__ w1,
                                              const float* __restrict__ w2,
                                              unsigned short* __restrict__ whi,
                                              unsigned short* __restrict__ wlo) {
    int i = blockIdx.x * 256 + threadIdx.x;   // [0, 3*4096)
    int which = i >> 12;
    int off = (i & 4095) * 4;
    const float* w = (which == 0) ? w0 : ((which == 1) ? w1 : w2);
    float4 v = *(const float4*)(w + off);
    ushort4 h = {f2b(v.x), f2b(v.y), f2b(v.z), f2b(v.w)};
    ushort4 l = {f2b(v.x - b2f(h.x)), f2b(v.y - b2f(h.y)),
                 f2b(v.z - b2f(h.z)), f2b(v.w - b2f(h.w))};
    *(ushort4*)(whi + (size_t)which * 16384 + off) = h;
    *(ushort4*)(wlo + (size_t)which * 16384 + off) = l;
}

// ---------------- fused layer kernel ----------------
// Per block: 16 nodes. Phase A: aggregate into fp32 LDS. Phase B: bf16-A x
// split-bf16-W MFMA GEMM + BN stats. xin/yout must be distinct (ping-pong).
// XMODE: 0 = x fp32 identity (layer 1), 1 = x bf16 with scale/shift.
// EMODE: 0 = sequential bf16 ebf, 1 = fallback fp32 eattr via eidx.
template <int XMODE, int EMODE>
__global__ __launch_bounds__(256) void layer_k(
        const float* __restrict__ xf, const unsigned short* __restrict__ xb,
        const float* __restrict__ scale, const float* __restrict__ shift,
        const unsigned short* __restrict__ ebf, const float* __restrict__ eattr,
        const int* __restrict__ eidx, const int* __restrict__ offsets,
        const int* __restrict__ csrc,
        const unsigned short* __restrict__ whi, const unsigned short* __restrict__ wlo,
        const float* __restrict__ bias, unsigned short* __restrict__ yb,
        double* __restrict__ gsum, double* __restrict__ gsumsq) {
    __shared__ float sS[16][DIM + 4];        // stride 528B
    __shared__ unsigned short ylds[16][136];

    int tid = threadIdx.x;
    int lane31 = tid & 31;
    int grp = tid >> 5;
    int n0 = blockIdx.x * 16;
    int f = lane31 * 4;

    float4 sc, sh;
    if (XMODE) {
        sc = *(const float4*)(scale + f);
        sh = *(const float4*)(shift + f);
    }

#pragma unroll
    for (int sub = 0; sub < 2; ++sub) {
        int n = n0 + grp * 2 + sub;
        float4 acc = make_float4(0.f, 0.f, 0.f, 0.f);
        int beg = offsets[n], end = offsets[n + 1];
        for (int b = beg; b < end; b += 32) {
            int kk = b + lane31;
            int s_l = (kk < end) ? csrc[kk] : 0;
            int e_l = 0;
            if (EMODE == 1) e_l = (kk < end) ? eidx[kk] : 0;
            int cnt = end - b;
            if (cnt > 32) cnt = 32;
#pragma unroll 4
            for (int t = 0; t < cnt; ++t) {
                int s = __shfl(s_l, t, 32);
                float4 ev;
                if (EMODE == 0) {
                    ushort4 eb = *(const ushort4*)(ebf + (size_t)(b + t) * DIM + f);
                    ev = make_float4(b2f(eb.x), b2f(eb.y), b2f(eb.z), b2f(eb.w));
                } else {
                    int e = __shfl(e_l, t, 32);
                    ev = *(const float4*)(eattr + (size_t)e * DIM + f);
                }
                float4 xv;
                if (XMODE == 0) {
                    xv = *(const float4*)(xf + (size_t)s * DIM + f);
                } else {
                    ushort4 u = *(const ushort4*)(xb + (size_t)s * DIM + f);
                    xv = make_float4(fmaf(b2f(u.x), sc.x, sh.x),
                                     fmaf(b2f(u.y), sc.y, sh.y),
                                     fmaf(b2f(u.z), sc.z, sh.z),
                                     fmaf(b2f(u.w), sc.w, sh.w));
                }
                acc.x += fmaxf(xv.x + ev.x, 0.f);
                acc.y += fmaxf(xv.y + ev.y, 0.f);
                acc.z += fmaxf(xv.z + ev.z, 0.f);
                acc.w += fmaxf(xv.w + ev.w, 0.f);
            }
        }
        float4 xn;
        if (XMODE == 0) {
            xn = *(const float4*)(xf + (size_t)n * DIM + f);
        } else {
            ushort4 u = *(const ushort4*)(xb + (size_t)n * DIM + f);
            xn = make_float4(fmaf(b2f(u.x), sc.x, sh.x), fmaf(b2f(u.y), sc.y, sh.y),
                             fmaf(b2f(u.z), sc.z, sh.z), fmaf(b2f(u.w), sc.w, sh.w));
        }
        float4 o = make_float4(xn.x + acc.x, xn.y + acc.y, xn.z + acc.z, xn.w + acc.w);
        *(float4*)(&sS[grp * 2 + sub][f]) = o;
    }
    __syncthreads();

    // ---- GEMM phase: A (bf16) x [Whi + Wlo] ----
    int wv = tid >> 6;
    int lane = tid & 63;
    int row = lane & 15;      // A row (node) / B col (dim)
    int kg = lane >> 4;       // k-group
    int d0 = wv * 32;
    const unsigned short* bh = whi + (size_t)(d0 + row) * DIM + kg * 8;
    const unsigned short* bl = wlo + (size_t)(d0 + row) * DIM + kg * 8;

    f32x4 acc0 = {0.f, 0.f, 0.f, 0.f};
    f32x4 acc1 = {0.f, 0.f, 0.f, 0.f};
#pragma unroll
    for (int ks = 0; ks < 4; ++ks) {
        const float* ap = &sS[row][kg * 8 + ks * 32];
        bf16x8 a;
#pragma unroll
        for (int j = 0; j < 8; ++j) a[j] = (short)f2b(ap[j]);
        bf16x8 b0h = *(const bf16x8*)(bh + ks * 32);
        bf16x8 b0l = *(const bf16x8*)(bl + ks * 32);
        bf16x8 b1h = *(const bf16x8*)(bh + 16 * DIM + ks * 32);
        bf16x8 b1l = *(const bf16x8*)(bl + 16 * DIM + ks * 32);
        acc0 = __builtin_amdgcn_mfma_f32_16x16x32_bf16(a, b0h, acc0, 0, 0, 0);
        acc0 = __builtin_amdgcn_mfma_f32_16x16x32_bf16(a, b0l, acc0, 0, 0, 0);
        acc1 = __builtin_amdgcn_mfma_f32_16x16x32_bf16(a, b1h, acc1, 0, 0, 0);
        acc1 = __builtin_amdgcn_mfma_f32_16x16x32_bf16(a, b1l, acc1, 0, 0, 0);
    }

    float bias0 = bias[d0 + row];
    float bias1 = bias[d0 + 16 + row];
    float s0 = 0.f, q0 = 0.f, s1 = 0.f, q1 = 0.f;
#pragma unroll
    for (int r = 0; r < 4; ++r) {
        int m = kg * 4 + r;
        float y0 = fmaxf(acc0[r] + bias0, 0.f);
        float y1 = fmaxf(acc1[r] + bias1, 0.f);
        ylds[m][d0 + row] = f2b(y0);
        ylds[m][d0 + 16 + row] = f2b(y1);
        s0 += y0; q0 += y0 * y0;
        s1 += y1; q1 += y1 * y1;
    }
    s0 += __shfl_xor(s0, 16); s0 += __shfl_xor(s0, 32);
    q0 += __shfl_xor(q0, 16); q0 += __shfl_xor(q0, 32);
    s1 += __shfl_xor(s1, 16); s1 += __shfl_xor(s1, 32);
    q1 += __shfl_xor(q1, 16); q1 += __shfl_xor(q1, 32);
    if (kg == 0) {
        atomicAdd(&gsum[d0 + row], (double)s0);
        atomicAdd(&gsumsq[d0 + row], (double)q0);
        atomicAdd(&gsum[d0 + 16 + row], (double)s1);
        atomicAdd(&gsumsq[d0 + 16 + row], (double)q1);
    }
    __syncthreads();
    int nrow = tid >> 4, seg = tid & 15;
    *(float4*)(yb + (size_t)(n0 + nrow) * DIM + seg * 8) =
        *(const float4*)(&ylds[nrow][seg * 8]);
}

// derive BN scale/shift; zero stats for next layer
__global__ void finalize_k(double* __restrict__ gsum, double* __restrict__ gsumsq,
                           const float* __restrict__ gamma, const float* __restrict__ beta,
                           float* __restrict__ scale, float* __restrict__ shift) {
    int d = threadIdx.x;
    if (d < DIM) {
        double mean = gsum[d] * (1.0 / NN);
        double var = gsumsq[d] * (1.0 / NN) - mean * mean;
        float sc = gamma[d] * rsqrtf((float)var + BN_EPS);
        scale[d] = sc;
        shift[d] = beta[d] - (float)mean * sc;
        gsum[d] = 0.0;
        gsumsq[d] = 0.0;
    }
}

__global__ __launch_bounds__(256) void norm_out_k(
        const unsigned short* __restrict__ yb, const float* __restrict__ scale,
        const float* __restrict__ shift, float* __restrict__ out) {
    int i = blockIdx.x * 256 + threadIdx.x;   // [0, NN*DIM/4)
    int f = (i & 31) * 4;
    ushort4 y = *(const ushort4*)(yb + (size_t)i * 4);
    float4 sc = *(const float4*)(scale + f);
    float4 sh = *(const float4*)(shift + f);
    float4 o;
    o.x = fmaf(b2f(y.x), sc.x, sh.x);
    o.y = fmaf(b2f(y.y), sc.y, sh.y);
    o.z = fmaf(b2f(y.z), sc.z, sh.z);
    o.w = fmaf(b2f(y.w), sc.w, sh.w);
    ((float4*)out)[i] = o;
}

// ---------------- launch ----------------

extern "C" void kernel_launch(void* const* d_in, const int* in_sizes, int n_in,
                              void* d_out, int out_size, void* d_ws, size_t ws_size,
                              hipStream_t stream) {
    const int* edge_index = (const int*)d_in[0];
    const int* srcs = edge_index;
    const int* dsts = edge_index + NE;
    const float* node_attr = (const float*)d_in[1];
    const float* eattr = (const float*)d_in[2];
    const float* Wp[3]    = {(const float*)d_in[3],  (const float*)d_in[7],  (const float*)d_in[11]};
    const float* bp[3]    = {(const float*)d_in[4],  (const float*)d_in[8],  (const float*)d_in[12]};
    const float* gammap[3]= {(const float*)d_in[5],  (const float*)d_in[9],  (const float*)d_in[13]};
    const float* betap[3] = {(const float*)d_in[6],  (const float*)d_in[10], (const float*)d_in[14]};

    size_t off = 0;
    char* base = (char*)d_ws;
    auto carve = [&](size_t bytes) -> void* {
        void* p = base + off;
        off += (bytes + 255) & ~(size_t)255;
        return p;
    };
    unsigned short* ybufA = (unsigned short*)carve((size_t)NN * DIM * 2);
    unsigned short* ybufB = (unsigned short*)carve((size_t)NN * DIM * 2);
    int* csrc    = (int*)carve((size_t)NE * 4);
    int* eidx    = (int*)carve((size_t)NE * 4);
    int* offsets = (int*)carve((size_t)(NN + 1) * 4);
    int* cursor  = (int*)carve((size_t)NN * 4);
    int* bsum    = (int*)carve((size_t)NCHUNK * 4);
    int* bbase   = (int*)carve((size_t)NCHUNK * 4);
    int* counts  = (int*)carve((size_t)NN * 4);
    double* gsum = (double*)carve(DIM * 8);
    double* gsumsq = (double*)carve(DIM * 8);
    float* scb   = (float*)carve(3 * DIM * 4);
    float* shb   = (float*)carve(3 * DIM * 4);
    unsigned short* whi = (unsigned short*)carve(3 * DIM * DIM * 2);
    unsigned short* wlo = (unsigned short*)carve(3 * DIM * DIM * 2);
    int use_ebf = (off + (size_t)NE * DIM * 2 <= ws_size);
    unsigned short* ebf = use_ebf ? (unsigned short*)carve((size_t)NE * DIM * 2) : nullptr;

    zero_k<<<NCHUNK, 256, 0, stream>>>(counts, gsum, gsumsq);
    count_k<<<(NE + 255) / 256, 256, 0, stream>>>(dsts, counts, NE);
    chunksum_k<<<NCHUNK, 256, 0, stream>>>(counts, bsum);
    chunkscan_k<<<1, 256, 0, stream>>>(bsum, bbase, offsets);
    scatteroff_k<<<NCHUNK, 256, 0, stream>>>(counts, bbase, offsets, cursor);
    if (use_ebf)
        fillcvt_k<true><<<(NE / 32 + 7) / 8, 256, 0, stream>>>(dsts, srcs, eattr, cursor,
                                                               csrc, eidx, ebf);
    else
        fillcvt_k<false><<<(NE / 32 + 7) / 8, 256, 0, stream>>>(dsts, srcs, eattr, cursor,
                                                                csrc, eidx, nullptr);
    wcvt_k<<<48, 256, 0, stream>>>(Wp[0], Wp[1], Wp[2], whi, wlo);

    // ---- layer 1: node_attr -> ybufA ----
    if (use_ebf)
        layer_k<0, 0><<<NN / 16, 256, 0, stream>>>(node_attr, nullptr, nullptr, nullptr,
                                                   ebf, eattr, eidx, offsets, csrc,
                                                   whi, wlo, bp[0], ybufA, gsum, gsumsq);
    else
        layer_k<0, 1><<<NN / 16, 256, 0, stream>>>(node_attr, nullptr, nullptr, nullptr,
                                                   nullptr, eattr, eidx, offsets, csrc,
                                                   whi, wlo, bp[0], ybufA, gsum, gsumsq);
    finalize_k<<<1, DIM, 0, stream>>>(gsum, gsumsq, gammap[0], betap[0], scb, shb);

    // ---- layers 2,3: ping-pong A->B->A ----
    unsigned short* xin = ybufA;
    unsigned short* yout = ybufB;
    for (int l = 1; l < 3; ++l) {
        const float* sc = scb + (l - 1) * DIM;
        const float* sh = shb + (l - 1) * DIM;
        if (use_ebf)
            layer_k<1, 0><<<NN / 16, 256, 0, stream>>>(nullptr, xin, sc, sh,
                                                       ebf, eattr, eidx, offsets, csrc,
                                                       whi + l * DIM * DIM, wlo + l * DIM * DIM,
                                                       bp[l], yout, gsum, gsumsq);
        else
            layer_k<1, 1><<<NN / 16, 256, 0, stream>>>(nullptr, xin, sc, sh,
                                                       nullptr, eattr, eidx, offsets, csrc,
                                                       whi + l * DIM * DIM, wlo + l * DIM * DIM,
                                                       bp[l], yout, gsum, gsumsq);
        finalize_k<<<1, DIM, 0, stream>>>(gsum, gsumsq, gammap[l], betap[l],
                                          scb + l * DIM, shb + l * DIM);
        unsigned short* t = xin; xin = yout; yout = t;
    }
    norm_out_k<<<NN * DIM / 4 / 256, 256, 0, stream>>>(xin, scb + 2 * DIM, shb + 2 * DIM,
                                                       (float*)d_out);
}